// Round 6
// baseline (746716.602 us; speedup 1.0000x reference)
//
#include <hip/hip_runtime.h>
#include <hip/hip_bf16.h>

// Decoder_62079457296567 — Tacotron2-style decoder, B=64 T_enc=300 T_dec=500 D=512 MEL=80 PRE=256
// Round 6: runtime INPUT-DTYPE DETECTION (fp32 vs bf16) + canonicalization to fp32 device globals.
// k_convert: detect + convert all 28 inputs into __device__ fp32 arrays (one-off, ~0.2ms).
// k_dec: persistent, 256 blocks x 256 threads, plain launch (<=10KB LDS, launch_bounds(256,2)
// => >=1 block/CU => all 256 blocks co-resident), own device-scope generation barrier.
// Output dtype mirrors detected input dtype.

#define DEV __device__ __forceinline__
typedef __hip_bfloat16 bf16;
typedef __hip_bfloat162 bf162;
DEV float b2f(bf16 x) { return __bfloat162float(x); }
DEV unsigned short f2us(float f) { bf16 h = __float2bfloat16(f); unsigned short u; __builtin_memcpy(&u, &h, 2); return u; }
DEV float us2f(unsigned short u) { union { float f; unsigned int i; } c; c.i = ((unsigned)u) << 16; return c.f; }

constexpr int NB = 256;

// ---------------- canonical fp32 inputs (device .bss, ~75 MB) ----------------
__device__ float g_enc[64*300*512];
__device__ float g_mel[64*500*80];
__device__ float g_w1[256*80];
__device__ float g_b1[256];
__device__ float g_w2[256*256];
__device__ float g_b2[256];
__device__ float g_awih[2048*768];
__device__ float g_awhh[2048*512];
__device__ float g_ab[2048];
__device__ float g_dwih[2048*1024];
__device__ float g_dwhh[2048*512];
__device__ float g_db[2048];
__device__ float g_qw[512*512];
__device__ float g_qpb[512];
__device__ float g_memwt[512*512];   // mem_w^T [k][d]
__device__ float g_memb[512];
__device__ float g_cw[32*2*31];
__device__ float g_cb[32];
__device__ float g_pw[512*32];
__device__ float g_vw[512];
__device__ float g_melw[80*512];
__device__ float g_melb[80];
__device__ float g_stopw[512];
__device__ float g_scal[2];          // v_b, stop_b
__device__ int   g_f32io;
// ---------------- recurrent state ----------------
__device__ float g_hatt[2*512*64];
__device__ float g_catt[512*64];
__device__ float g_hdec[2*512*64];
__device__ float g_cdec[512*64];
__device__ float g_ctx[512*64];
__device__ float g_a[64*300];
__device__ float g_acum[64*300];
__device__ float g_pmt[256*64];
__device__ float g_pm1t[256*64];
__device__ float g_qt[512*64];
__device__ float g_e[64*300];
__device__ int   g_cnt = 0;
__device__ int   g_gen = 0;

struct InPtrs { const void* p[28]; };

DEV float sigf(float x) { return 1.f / (1.f + __expf(-x)); }
DEV float tanhf_fast(float x) {
  float e = __expf(-2.f * fabsf(x));
  float r = (1.f - e) / (1.f + e);
  return copysignf(r, x);
}

// If inputs are fp32 and we read shorts, the EVEN-indexed shorts are fp32 mantissa
// bits -> uniform exponent field -> ~48% have |v|>64. Real bf16 N(0,1): never.
DEV int detect_f32(const void* enc_raw) {
  const unsigned short* u = (const unsigned short*)enc_raw;
  int big = 0;
  for (int i = 0; i < 256; i += 2) { int e = (u[i] >> 7) & 0xFF; big += (e > 133) ? 1 : 0; }
  return big >= 8 ? 1 : 0;
}

DEV float ldin(const void* p, int i, int f32) {
  return f32 ? ((const float*)p)[i] : b2f(((const bf16*)p)[i]);
}

// ---------------- conversion kernel ----------------
__global__ __launch_bounds__(256) void k_convert(InPtrs P) {
  const int NT = gridDim.x * 256;
  const int flat = blockIdx.x * 256 + threadIdx.x;
  const int f32 = detect_f32(P.p[0]);
  if (flat == 0) {
    g_f32io = f32;
    g_scal[0] = ldin(P.p[23], 0, f32);
    g_scal[1] = ldin(P.p[27], 0, f32);
  }
#define CVT(dst, idx, n) for (int i = flat; i < (n); i += NT) dst[i] = ldin(P.p[idx], i, f32);
  CVT(g_enc, 0, 64*300*512)
  CVT(g_mel, 1, 64*500*80)
  CVT(g_w1, 2, 256*80)   CVT(g_b1, 3, 256)
  CVT(g_w2, 4, 256*256)  CVT(g_b2, 5, 256)
  CVT(g_awih, 6, 2048*768)  CVT(g_awhh, 7, 2048*512)
  CVT(g_dwih, 10, 2048*1024) CVT(g_dwhh, 11, 2048*512)
  CVT(g_qw, 14, 512*512)
  CVT(g_cw, 18, 32*2*31) CVT(g_cb, 19, 32)
  CVT(g_pw, 20, 512*32)  CVT(g_vw, 22, 512)
  CVT(g_melw, 24, 80*512) CVT(g_melb, 25, 80)
  CVT(g_stopw, 26, 512)  CVT(g_memb, 17, 512)
#undef CVT
  for (int i = flat; i < 2048; i += NT) g_ab[i] = ldin(P.p[8], i, f32) + ldin(P.p[9], i, f32);
  for (int i = flat; i < 2048; i += NT) g_db[i] = ldin(P.p[12], i, f32) + ldin(P.p[13], i, f32);
  for (int i = flat; i < 512; i += NT) g_qpb[i] = ldin(P.p[15], i, f32) + ldin(P.p[21], i, f32);
  for (int o = flat; o < 512*512; o += NT) {
    int d = o >> 9, k = o & 511;
    g_memwt[(size_t)k*512 + d] = ldin(P.p[16], o, f32);
  }
}

// device-scope generation barrier; all NB blocks call it identically
DEV void gbar() {
  __syncthreads();
  if (threadIdx.x == 0) {
    __threadfence();
    int g = __hip_atomic_load(&g_gen, __ATOMIC_RELAXED, __HIP_MEMORY_SCOPE_AGENT);
    int arrived = __hip_atomic_fetch_add(&g_cnt, 1, __ATOMIC_ACQ_REL, __HIP_MEMORY_SCOPE_AGENT);
    if (arrived == NB - 1) {
      __hip_atomic_store(&g_cnt, 0, __ATOMIC_RELAXED, __HIP_MEMORY_SCOPE_AGENT);
      __hip_atomic_fetch_add(&g_gen, 1, __ATOMIC_RELEASE, __HIP_MEMORY_SCOPE_AGENT);
    } else {
      while (__hip_atomic_load(&g_gen, __ATOMIC_ACQUIRE, __HIP_MEMORY_SCOPE_AGENT) == g)
        __builtin_amdgcn_s_sleep(8);
    }
    __threadfence();
  }
  __syncthreads();
}

// 4 simultaneous dots over xT[k][b] (lanes=b); fp32 weight rows wave-uniform (scalar loads).
DEV void dot4f(const float* X, int n, const float* w0, const float* w1,
               const float* w2, const float* w3, int lane,
               float& a0, float& a1, float& a2, float& a3) {
#pragma unroll 4
  for (int k = 0; k < n; k += 4) {
    float x0 = X[(k+0)*64 + lane];
    float x1 = X[(k+1)*64 + lane];
    float x2 = X[(k+2)*64 + lane];
    float x3 = X[(k+3)*64 + lane];
    float4 u0 = *(const float4*)(w0 + k);
    float4 u1 = *(const float4*)(w1 + k);
    float4 u2 = *(const float4*)(w2 + k);
    float4 u3 = *(const float4*)(w3 + k);
    a0 = fmaf(u0.x,x0,a0); a0 = fmaf(u0.y,x1,a0); a0 = fmaf(u0.z,x2,a0); a0 = fmaf(u0.w,x3,a0);
    a1 = fmaf(u1.x,x0,a1); a1 = fmaf(u1.y,x1,a1); a1 = fmaf(u1.z,x2,a1); a1 = fmaf(u1.w,x3,a1);
    a2 = fmaf(u2.x,x0,a2); a2 = fmaf(u2.y,x1,a2); a2 = fmaf(u2.z,x2,a2); a2 = fmaf(u2.w,x3,a2);
    a3 = fmaf(u3.x,x0,a3); a3 = fmaf(u3.y,x1,a3); a3 = fmaf(u3.z,x2,a3); a3 = fmaf(u3.w,x3,a3);
  }
}

__global__ __launch_bounds__(256, 2) void k_dec(void* outv) {
  const int bb = blockIdx.x;
  const int tid = threadIdx.x;
  const int lane = tid & 63, wv = tid >> 6;
  const int f32io = g_f32io;
  bf16* outh = (bf16*)outv;
  float* outf = (float*)outv;

  __shared__ float sbuf[2432];     // 9.7KB: enc stage / conv [75][32] / softmax pl+red
  __shared__ float part[4][76];

  const int eb = bb >> 2, tt0 = (bb & 3) * 75;   // energy-role: (batch, tt-chunk)
  const int d1 = wv*128 + lane;                  // this thread covers d1 and d1+64

  // ---- Pr0: zero state; pre1(0) on blocks 192..255 ----
  {
    const int flat = bb*256 + tid;
    for (int i = flat; i < 2*512*64; i += NB*256) { g_hatt[i] = 0.f; g_hdec[i] = 0.f; }
    for (int i = flat; i < 512*64; i += NB*256) { g_catt[i] = 0.f; g_cdec[i] = 0.f; g_ctx[i] = 0.f; }
    for (int i = flat; i < 64*300; i += NB*256) { g_a[i] = 0.f; g_acum[i] = 0.f; }
    if (bb >= 192) {
      int f3 = (bb - 192)*256 + tid;
      int b_ = f3 & 63; int ii = __builtin_amdgcn_readfirstlane(f3 >> 6);
      float acc = g_b1[ii];
      const float* wr = g_w1 + ii*80;
      const float* mi = g_mel + (size_t)b_*500*80;
      for (int m = 0; m < 80; ++m) acc = fmaf(wr[m], mi[m], acc);
      g_pm1t[ii*64 + b_] = fmaxf(acc, 0.f);
    }
  }
  gbar();

  // ---- Pr1: mproj chunk -> registers (packed bf16x2); pre2(0) on blocks 64..127 ----
  unsigned int mpq[75];
  {
    float a1[75], a2[75];
#pragma unroll
    for (int r = 0; r < 75; ++r) { a1[r] = 0.f; a2[r] = 0.f; }
    for (int kt = 0; kt < 16; ++kt) {
      __syncthreads();
      for (int i = tid; i < 75*32; i += 256) {
        int r = i >> 5, kk = i & 31;
        sbuf[i] = g_enc[((size_t)eb*300 + tt0 + r)*512 + kt*32 + kk];
      }
      __syncthreads();
      for (int kk = 0; kk < 32; ++kk) {
        int k = kt*32 + kk;
        float w1 = g_memwt[(size_t)k*512 + d1];
        float w2 = g_memwt[(size_t)k*512 + d1 + 64];
#pragma unroll
        for (int r = 0; r < 75; ++r) {
          float ev = sbuf[r*32 + kk];
          a1[r] = fmaf(ev, w1, a1[r]);
          a2[r] = fmaf(ev, w2, a2[r]);
        }
      }
    }
    const float mb1 = g_memb[d1], mb2 = g_memb[d1 + 64];
#pragma unroll
    for (int r = 0; r < 75; ++r)
      mpq[r] = (unsigned)f2us(a1[r] + mb1) | ((unsigned)f2us(a2[r] + mb2) << 16);
    if (bb >= 64 && bb < 128) {  // pre2(0)
      int f4 = (bb - 64)*256 + tid;
      int b_ = f4 & 63; int i2 = __builtin_amdgcn_readfirstlane(f4 >> 6);
      float acc = g_b2[i2];
      const float* wr = g_w2 + i2*256;
      for (int k = 0; k < 256; k += 4) {
        float4 u = *(const float4*)(wr + k);
        acc = fmaf(u.x, g_pm1t[(k+0)*64 + b_], acc);
        acc = fmaf(u.y, g_pm1t[(k+1)*64 + b_], acc);
        acc = fmaf(u.z, g_pm1t[(k+2)*64 + b_], acc);
        acc = fmaf(u.w, g_pm1t[(k+3)*64 + b_], acc);
      }
      g_pmt[i2*64 + b_] = fmaxf(acc, 0.f);
    }
  }
  // permanent per-thread constants for the energy phase
  float Pa[32], Pb[32];
#pragma unroll
  for (int i = 0; i < 8; ++i) {
    float4 u = *(const float4*)(g_pw + (size_t)d1*32 + 4*i);
    float4 w = *(const float4*)(g_pw + (size_t)(d1+64)*32 + 4*i);
    Pa[4*i] = u.x; Pa[4*i+1] = u.y; Pa[4*i+2] = u.z; Pa[4*i+3] = u.w;
    Pb[4*i] = w.x; Pb[4*i+1] = w.y; Pb[4*i+2] = w.z; Pb[4*i+3] = w.w;
  }
  const float v1 = g_vw[d1], v2 = g_vw[d1 + 64];
  const float vb = g_scal[0];
  gbar();

  // ================= main loop =================
  for (int t = 0; t <= 500; ++t) {
    const int rp = t & 1, wp = rp ^ 1;

    // ---- P1: att-LSTM(t) [0..127] | dec-LSTM(t-1) [128..255] ----
    if (bb < 128) {
      if (t < 500) {
        const int j = __builtin_amdgcn_readfirstlane(bb*4 + wv);
        float ai = g_ab[j], af = g_ab[512+j], ag = g_ab[1024+j], ao = g_ab[1536+j];
        dot4f(g_pmt, 256, g_awih + (size_t)j*768, g_awih + (size_t)(512+j)*768,
              g_awih + (size_t)(1024+j)*768, g_awih + (size_t)(1536+j)*768, lane, ai, af, ag, ao);
        dot4f(g_ctx, 512, g_awih + (size_t)j*768 + 256, g_awih + (size_t)(512+j)*768 + 256,
              g_awih + (size_t)(1024+j)*768 + 256, g_awih + (size_t)(1536+j)*768 + 256, lane, ai, af, ag, ao);
        dot4f(g_hatt + rp*(512*64), 512, g_awhh + (size_t)j*512, g_awhh + (size_t)(512+j)*512,
              g_awhh + (size_t)(1024+j)*512, g_awhh + (size_t)(1536+j)*512, lane, ai, af, ag, ao);
        float c = g_catt[j*64 + lane];
        float cn = sigf(af)*c + sigf(ai)*tanhf_fast(ag);
        float hn = sigf(ao)*tanhf_fast(cn);
        g_catt[j*64 + lane] = cn;
        g_hatt[wp*(512*64) + j*64 + lane] = hn;
      }
    } else {
      if (t > 0) {
        const int j = __builtin_amdgcn_readfirstlane((bb-128)*4 + wv);
        float ai = g_db[j], af = g_db[512+j], ag = g_db[1024+j], ao = g_db[1536+j];
        dot4f(g_hatt + rp*(512*64), 512, g_dwih + (size_t)j*1024, g_dwih + (size_t)(512+j)*1024,
              g_dwih + (size_t)(1024+j)*1024, g_dwih + (size_t)(1536+j)*1024, lane, ai, af, ag, ao);
        dot4f(g_ctx, 512, g_dwih + (size_t)j*1024 + 512, g_dwih + (size_t)(512+j)*1024 + 512,
              g_dwih + (size_t)(1024+j)*1024 + 512, g_dwih + (size_t)(1536+j)*1024 + 512, lane, ai, af, ag, ao);
        dot4f(g_hdec + wp*(512*64), 512, g_dwhh + (size_t)j*512, g_dwhh + (size_t)(512+j)*512,
              g_dwhh + (size_t)(1024+j)*512, g_dwhh + (size_t)(1536+j)*512, lane, ai, af, ag, ao);
        float c = g_cdec[j*64 + lane];
        float cn = sigf(af)*c + sigf(ai)*tanhf_fast(ag);
        float hn = sigf(ao)*tanhf_fast(cn);
        g_cdec[j*64 + lane] = cn;
        g_hdec[rp*(512*64) + j*64 + lane] = hn;
      }
    }
    gbar();

    // ---- P2: q(t) [0..127] | mel(t-1) [128..147] | stop(t-1) [148] | pre1(t+1) [192..255] ----
    if (bb < 128) {
      if (t < 500) {
        int f = bb*256 + tid;
        int b_ = f & 63; int dq = __builtin_amdgcn_readfirstlane(f >> 6);
        float acc = g_qpb[dq];
        const float* wr = g_qw + (size_t)dq*512;
        const float* H = g_hatt + wp*(512*64);
        for (int k = 0; k < 512; k += 4) {
          float4 u = *(const float4*)(wr + k);
          acc = fmaf(u.x, H[(k+0)*64 + b_], acc);
          acc = fmaf(u.y, H[(k+1)*64 + b_], acc);
          acc = fmaf(u.z, H[(k+2)*64 + b_], acc);
          acc = fmaf(u.w, H[(k+3)*64 + b_], acc);
        }
        g_qt[dq*64 + b_] = acc;
      }
    } else if (bb < 148) {
      if (t > 0) {
        int f2 = (bb - 128)*256 + tid;  // < 5120
        int b_ = f2 & 63; int m = __builtin_amdgcn_readfirstlane(f2 >> 6);
        const float* HD = g_hdec + rp*(512*64);
        float acc = g_melb[m];
        const float* wr = g_melw + (size_t)m*512;
        for (int k = 0; k < 512; k += 4) {
          float4 u = *(const float4*)(wr + k);
          acc = fmaf(u.x, HD[(k+0)*64 + b_], acc);
          acc = fmaf(u.y, HD[(k+1)*64 + b_], acc);
          acc = fmaf(u.z, HD[(k+2)*64 + b_], acc);
          acc = fmaf(u.w, HD[(k+3)*64 + b_], acc);
        }
        size_t oidx = (size_t)(b_*500 + (t-1))*80 + m;
        if (f32io) outf[oidx] = acc; else outh[oidx] = __float2bfloat16(acc);
      }
    } else if (bb == 148) {
      if (t > 0 && tid < 64) {
        int b_ = tid;
        const float* HD = g_hdec + rp*(512*64);
        float acc = g_scal[1];
        for (int k = 0; k < 512; k += 4) {
          float4 u = *(const float4*)(g_stopw + k);
          acc = fmaf(u.x, HD[(k+0)*64 + b_], acc);
          acc = fmaf(u.y, HD[(k+1)*64 + b_], acc);
          acc = fmaf(u.z, HD[(k+2)*64 + b_], acc);
          acc = fmaf(u.w, HD[(k+3)*64 + b_], acc);
        }
        size_t oidx = 2560000 + b_*500 + (t-1);
        if (f32io) outf[oidx] = acc; else outh[oidx] = __float2bfloat16(acc);
      }
    } else if (bb >= 192) {
      if (t <= 498) {
        int f3 = (bb - 192)*256 + tid;
        int b_ = f3 & 63; int ii = __builtin_amdgcn_readfirstlane(f3 >> 6);
        float acc = g_b1[ii];
        const float* wr = g_w1 + ii*80;
        const float* mi = g_mel + (size_t)(b_*500 + t + 1)*80;
        for (int m = 0; m < 80; ++m) acc = fmaf(wr[m], mi[m], acc);
        g_pm1t[ii*64 + b_] = fmaxf(acc, 0.f);
      }
    }
    gbar();

    // ---- P3: energies e(t), all 256 blocks ----
    if (t < 500) {
      for (int i = tid; i < 75*32; i += 256) {   // conv into sbuf [75 tt][32 c]
        int ttl = i >> 5, c2 = i & 31;
        int tt = tt0 + ttl;
        float s = g_cb[c2];
        for (int k = 0; k < 31; ++k) {
          int src = tt + k - 15;
          if (src >= 0 && src < 300) {
            s = fmaf(g_cw[c2*62 + k],      g_a[eb*300 + src], s);
            s = fmaf(g_cw[c2*62 + 31 + k], g_acum[eb*300 + src], s);
          }
        }
        sbuf[i] = s;
      }
      __syncthreads();
      const float q1 = g_qt[d1*64 + eb], q2 = g_qt[(d1+64)*64 + eb];
#pragma unroll
      for (int i = 0; i < 75; ++i) {
        float s1 = q1 + us2f((unsigned short)(mpq[i] & 0xffffu));
        float s2 = q2 + us2f((unsigned short)(mpq[i] >> 16));
#pragma unroll
        for (int c = 0; c < 32; ++c) {
          float cv = sbuf[i*32 + c];
          s1 = fmaf(Pa[c], cv, s1);
          s2 = fmaf(Pb[c], cv, s2);
        }
        float p = v1*tanhf_fast(s1) + v2*tanhf_fast(s2);
#pragma unroll
        for (int m = 32; m >= 1; m >>= 1) p += __shfl_xor(p, m, 64);
        if (lane == 0) part[wv][i] = p;
      }
      __syncthreads();
      if (tid < 75)
        g_e[eb*300 + tt0 + tid] =
            part[0][tid] + part[1][tid] + part[2][tid] + part[3][tid] + vb;
    }
    gbar();

    // ---- P4: softmax + a/a_cum + ctx(t) [0..63] | pre2(t+1) [64..127] ----
    if (t < 500) {
      if (bb < 64) {
        float* pl = sbuf; float* red = sbuf + 304;
        const int b_ = bb;
        const float* Ep = g_e + b_*300;
        float e1 = Ep[tid];
        float e2 = (tid + 256 < 300) ? Ep[tid + 256] : -3e38f;
        red[tid] = fmaxf(e1, e2); __syncthreads();
        for (int s = 128; s > 0; s >>= 1) { if (tid < s) red[tid] = fmaxf(red[tid], red[tid+s]); __syncthreads(); }
        float mx = red[0]; __syncthreads();
        float p1 = __expf(e1 - mx);
        float p2 = (tid + 256 < 300) ? __expf(e2 - mx) : 0.f;
        pl[tid] = p1;
        if (tid + 256 < 300) pl[tid + 256] = p2;
        red[tid] = p1 + p2; __syncthreads();
        for (int s = 128; s > 0; s >>= 1) { if (tid < s) red[tid] += red[tid+s]; __syncthreads(); }
        const float inv = 1.f / red[0];
        float av = pl[tid]*inv;
        g_a[b_*300 + tid] = av; g_acum[b_*300 + tid] += av;
        if (tid + 256 < 300) {
          float av2 = pl[tid+256]*inv;
          g_a[b_*300 + tid+256] = av2; g_acum[b_*300 + tid+256] += av2;
        }
        __syncthreads();
        const float* ep = g_enc + (size_t)(b_*300)*512;
#pragma unroll
        for (int h = 0; h < 2; ++h) {
          int dd = tid + h*256;
          float acc = 0.f;
          for (int tt = 0; tt < 300; ++tt) acc = fmaf(pl[tt], ep[(size_t)tt*512 + dd], acc);
          g_ctx[dd*64 + b_] = acc * inv;
        }
      } else if (bb < 128) {
        if (t <= 498) {
          int f4 = (bb - 64)*256 + tid;
          int b_ = f4 & 63; int i2 = __builtin_amdgcn_readfirstlane(f4 >> 6);
          float acc = g_b2[i2];
          const float* wr = g_w2 + i2*256;
          for (int k = 0; k < 256; k += 4) {
            float4 u = *(const float4*)(wr + k);
            acc = fmaf(u.x, g_pm1t[(k+0)*64 + b_], acc);
            acc = fmaf(u.y, g_pm1t[(k+1)*64 + b_], acc);
            acc = fmaf(u.z, g_pm1t[(k+2)*64 + b_], acc);
            acc = fmaf(u.w, g_pm1t[(k+3)*64 + b_], acc);
          }
          g_pmt[i2*64 + b_] = fmaxf(acc, 0.f);
        }
      }
    }
    gbar();
  }
}

// ---------------- host ----------------
extern "C" void kernel_launch(void* const* d_in, const int* in_sizes, int n_in,
                              void* d_out, int out_size, void* d_ws, size_t ws_size,
                              hipStream_t stream) {
  (void)d_ws; (void)ws_size;
  InPtrs P;
  for (int i = 0; i < 28 && i < n_in; ++i) P.p[i] = d_in[i];
  k_convert<<<dim3(2048), dim3(256), 0, stream>>>(P);
  k_dec<<<dim3(NB), dim3(256), 0, stream>>>(d_out);
}

// Round 7
// 284037.915 us; speedup vs baseline: 2.6289x; 2.6289x over previous
//
#include <hip/hip_runtime.h>
#include <hip/hip_bf16.h>

// Decoder_62079457296567 — Tacotron2-style decoder, B=64 T_enc=300 T_dec=500 D=512 MEL=80 PRE=256
// Round 7: R6 pipeline (passed, 747ms) with the stall structure fixed:
//  - flag/relay grid barrier (relaxed polls, no RMW contention, 2 fences/block/barrier)
//  - 3 barriers/step (q folded into energy phase via qwT; mel/stop/pre1 into energy phase)
//  - wave-uniform weight loads forced to VMEM broadcast via opaque zero (asm v_mov) index
// Plain launch: 256 blocks x 256 threads, <=10KB LDS -> guaranteed co-resident.

#define DEV __device__ __forceinline__
typedef __hip_bfloat16 bf16;
DEV float b2f(bf16 x) { return __bfloat162float(x); }
DEV unsigned short f2us(float f) { bf16 h = __float2bfloat16(f); unsigned short u; __builtin_memcpy(&u, &h, 2); return u; }
DEV float us2f(unsigned short u) { union { float f; unsigned int i; } c; c.i = ((unsigned)u) << 16; return c.f; }

constexpr int NB = 256;

// ---------------- canonical fp32 inputs (device .bss) ----------------
__device__ float g_enc[64*300*512];
__device__ float g_mel[64*500*80];
__device__ float g_w1[256*80];
__device__ float g_b1[256];
__device__ float g_w2[256*256];
__device__ float g_b2[256];
__device__ float g_awih[2048*768];
__device__ float g_awhh[2048*512];
__device__ float g_ab[2048];
__device__ float g_dwih[2048*1024];
__device__ float g_dwhh[2048*512];
__device__ float g_db[2048];
__device__ float g_qwt[512*512];     // q_w^T [k][d]
__device__ float g_qpb[512];
__device__ float g_memwt[512*512];   // mem_w^T [k][d]
__device__ float g_memb[512];
__device__ float g_cw[32*2*31];
__device__ float g_cb[32];
__device__ float g_pw[512*32];
__device__ float g_vw[512];
__device__ float g_melw[80*512];
__device__ float g_melb[80];
__device__ float g_stopw[512];
__device__ float g_scal[2];          // v_b, stop_b
__device__ int   g_f32io;
// ---------------- recurrent state ----------------
__device__ float g_hatt[2*512*64];
__device__ float g_catt[512*64];
__device__ float g_hdec[2*512*64];
__device__ float g_cdec[512*64];
__device__ float g_ctx[512*64];
__device__ float g_a[64*300];
__device__ float g_acum[64*300];
__device__ float g_pmt[256*64];
__device__ float g_pm1t[256*64];
__device__ float g_e[64*300];
// ---------------- barrier (flag relay; zeroed by k_convert each launch) ----------------
__device__ int g_flag[NB*32];        // one line per block
__device__ int g_go[16*32];          // replicated go word

struct InPtrs { const void* p[28]; };

DEV float sigf(float x) { return 1.f / (1.f + __expf(-x)); }
DEV float tanhf_fast(float x) {
  float e = __expf(-2.f * fabsf(x));
  float r = (1.f - e) / (1.f + e);
  return copysignf(r, x);
}
DEV int zero_vgpr() { int z; asm volatile("v_mov_b32 %0, 0" : "=v"(z)); return z; }

DEV int detect_f32(const void* enc_raw) {
  const unsigned short* u = (const unsigned short*)enc_raw;
  int big = 0;
  for (int i = 0; i < 256; i += 2) { int e = (u[i] >> 7) & 0xFF; big += (e > 133) ? 1 : 0; }
  return big >= 8 ? 1 : 0;
}
DEV float ldin(const void* p, int i, int f32) {
  return f32 ? ((const float*)p)[i] : b2f(((const bf16*)p)[i]);
}

// ---------------- conversion kernel (also zeroes state + barrier) ----------------
__global__ __launch_bounds__(256) void k_convert(InPtrs P) {
  const int NT = gridDim.x * 256;
  const int flat = blockIdx.x * 256 + threadIdx.x;
  const int f32 = detect_f32(P.p[0]);
  if (flat == 0) {
    g_f32io = f32;
    g_scal[0] = ldin(P.p[23], 0, f32);
    g_scal[1] = ldin(P.p[27], 0, f32);
  }
#define CVT(dst, idx, n) for (int i = flat; i < (n); i += NT) dst[i] = ldin(P.p[idx], i, f32);
  CVT(g_enc, 0, 64*300*512)
  CVT(g_mel, 1, 64*500*80)
  CVT(g_w1, 2, 256*80)   CVT(g_b1, 3, 256)
  CVT(g_w2, 4, 256*256)  CVT(g_b2, 5, 256)
  CVT(g_awih, 6, 2048*768)  CVT(g_awhh, 7, 2048*512)
  CVT(g_dwih, 10, 2048*1024) CVT(g_dwhh, 11, 2048*512)
  CVT(g_cw, 18, 32*2*31) CVT(g_cb, 19, 32)
  CVT(g_pw, 20, 512*32)  CVT(g_vw, 22, 512)
  CVT(g_melw, 24, 80*512) CVT(g_melb, 25, 80)
  CVT(g_stopw, 26, 512)  CVT(g_memb, 17, 512)
#undef CVT
  for (int i = flat; i < 2048; i += NT) g_ab[i] = ldin(P.p[8], i, f32) + ldin(P.p[9], i, f32);
  for (int i = flat; i < 2048; i += NT) g_db[i] = ldin(P.p[12], i, f32) + ldin(P.p[13], i, f32);
  for (int i = flat; i < 512; i += NT) g_qpb[i] = ldin(P.p[15], i, f32) + ldin(P.p[21], i, f32);
  for (int o = flat; o < 512*512; o += NT) {
    int d = o >> 9, k = o & 511;
    g_memwt[(size_t)k*512 + d] = ldin(P.p[16], o, f32);
    g_qwt[(size_t)k*512 + d]   = ldin(P.p[14], o, f32);
  }
  // zero state + barrier
  for (int i = flat; i < 2*512*64; i += NT) { g_hatt[i] = 0.f; g_hdec[i] = 0.f; }
  for (int i = flat; i < 512*64; i += NT) { g_catt[i] = 0.f; g_cdec[i] = 0.f; g_ctx[i] = 0.f; }
  for (int i = flat; i < 64*300; i += NT) { g_a[i] = 0.f; g_acum[i] = 0.f; }
  for (int i = flat; i < NB*32; i += NT) g_flag[i] = 0;
  for (int i = flat; i < 16*32; i += NT) g_go[i] = 0;
}

// ---------------- flag/relay grid barrier ----------------
DEV void gbar(int n, int bb, int tid) {
  __syncthreads();
  if (tid == 0) {
    __threadfence();   // release our writes agent-wide
    __hip_atomic_store(&g_flag[bb*32], n, __ATOMIC_RELAXED, __HIP_MEMORY_SCOPE_AGENT);
  }
  if (bb == 0) {
    while (__hip_atomic_load(&g_flag[tid*32], __ATOMIC_RELAXED, __HIP_MEMORY_SCOPE_AGENT) < n)
      __builtin_amdgcn_s_sleep(1);
    __syncthreads();
    if (tid == 0) __threadfence();   // full fence: relay point
    __syncthreads();
    if (tid < 16)
      __hip_atomic_store(&g_go[tid*32], n, __ATOMIC_RELAXED, __HIP_MEMORY_SCOPE_AGENT);
  } else {
    if (tid == 0) {
      while (__hip_atomic_load(&g_go[(bb>>4)*32], __ATOMIC_RELAXED, __HIP_MEMORY_SCOPE_AGENT) < n)
        __builtin_amdgcn_s_sleep(1);
      __threadfence();   // acquire remote writes
    }
  }
  __syncthreads();
}

// 4 simultaneous dots over xT[k][b] (lanes=b); weight rows via VMEM broadcast (z-trick).
DEV void dot4f(const float* X, int n, const float* w0, const float* w1,
               const float* w2, const float* w3, int lane, int z,
               float& a0, float& a1, float& a2, float& a3) {
  const float* p0 = w0 + z; const float* p1 = w1 + z;
  const float* p2 = w2 + z; const float* p3 = w3 + z;
#pragma unroll 4
  for (int k = 0; k < n; k += 4) {
    float x0 = X[(k+0)*64 + lane];
    float x1 = X[(k+1)*64 + lane];
    float x2 = X[(k+2)*64 + lane];
    float x3 = X[(k+3)*64 + lane];
    float4 u0 = *(const float4*)(p0 + k);
    float4 u1 = *(const float4*)(p1 + k);
    float4 u2 = *(const float4*)(p2 + k);
    float4 u3 = *(const float4*)(p3 + k);
    a0 = fmaf(u0.x,x0,a0); a0 = fmaf(u0.y,x1,a0); a0 = fmaf(u0.z,x2,a0); a0 = fmaf(u0.w,x3,a0);
    a1 = fmaf(u1.x,x0,a1); a1 = fmaf(u1.y,x1,a1); a1 = fmaf(u1.z,x2,a1); a1 = fmaf(u1.w,x3,a1);
    a2 = fmaf(u2.x,x0,a2); a2 = fmaf(u2.y,x1,a2); a2 = fmaf(u2.z,x2,a2); a2 = fmaf(u2.w,x3,a2);
    a3 = fmaf(u3.x,x0,a3); a3 = fmaf(u3.y,x1,a3); a3 = fmaf(u3.z,x2,a3); a3 = fmaf(u3.w,x3,a3);
  }
}

__global__ __launch_bounds__(256) void k_dec(void* outv) {
  const int bb = blockIdx.x;
  const int tid = threadIdx.x;
  const int lane = tid & 63, wv = tid >> 6;
  const int z = zero_vgpr();
  const int f32io = g_f32io;
  bf16* outh = (bf16*)outv;
  float* outf = (float*)outv;

  __shared__ float sbuf[2432];
  __shared__ float part[4][76];

  const int eb = bb >> 2, tt0 = (bb & 3) * 75;
  const int d1 = wv*128 + lane;
  int bn = 0;

  // ---- Pr0: pre1(0) on blocks 192..255 ----
  if (bb >= 192) {
    int f3 = (bb - 192)*256 + tid;
    int b_ = f3 & 63; int ii = __builtin_amdgcn_readfirstlane(f3 >> 6);
    float acc = g_b1[ii];
    const float* wr = g_w1 + ii*80 + z;
    const float* mi = g_mel + (size_t)b_*500*80;
    for (int m = 0; m < 80; ++m) acc = fmaf(wr[m], mi[m], acc);
    g_pm1t[ii*64 + b_] = fmaxf(acc, 0.f);
  }
  gbar(++bn, bb, tid);

  // ---- Pr1: mproj chunk -> registers (packed bf16x2); pre2(0) on blocks 64..127 ----
  unsigned int mpq[75];
  {
    float a1[75], a2[75];
#pragma unroll
    for (int r = 0; r < 75; ++r) { a1[r] = 0.f; a2[r] = 0.f; }
    for (int kt = 0; kt < 16; ++kt) {
      __syncthreads();
      for (int i = tid; i < 75*32; i += 256) {
        int r = i >> 5, kk = i & 31;
        sbuf[i] = g_enc[((size_t)eb*300 + tt0 + r)*512 + kt*32 + kk];
      }
      __syncthreads();
      for (int kk = 0; kk < 32; ++kk) {
        int k = kt*32 + kk;
        float w1 = g_memwt[(size_t)k*512 + d1];
        float w2 = g_memwt[(size_t)k*512 + d1 + 64];
#pragma unroll
        for (int r = 0; r < 75; ++r) {
          float ev = sbuf[r*32 + kk];
          a1[r] = fmaf(ev, w1, a1[r]);
          a2[r] = fmaf(ev, w2, a2[r]);
        }
      }
    }
    const float mb1 = g_memb[d1], mb2 = g_memb[d1 + 64];
#pragma unroll
    for (int r = 0; r < 75; ++r)
      mpq[r] = (unsigned)f2us(a1[r] + mb1) | ((unsigned)f2us(a2[r] + mb2) << 16);
    if (bb >= 64 && bb < 128) {  // pre2(0)
      int f4 = (bb - 64)*256 + tid;
      int b_ = f4 & 63; int i2 = __builtin_amdgcn_readfirstlane(f4 >> 6);
      float acc = g_b2[i2];
      const float* wr = g_w2 + i2*256 + z;
      for (int k = 0; k < 256; k += 4) {
        float4 u = *(const float4*)(wr + k);
        acc = fmaf(u.x, g_pm1t[(k+0)*64 + b_], acc);
        acc = fmaf(u.y, g_pm1t[(k+1)*64 + b_], acc);
        acc = fmaf(u.z, g_pm1t[(k+2)*64 + b_], acc);
        acc = fmaf(u.w, g_pm1t[(k+3)*64 + b_], acc);
      }
      g_pmt[i2*64 + b_] = fmaxf(acc, 0.f);
    }
  }
  float Pa[32], Pb[32];
#pragma unroll
  for (int i = 0; i < 8; ++i) {
    float4 u = *(const float4*)(g_pw + (size_t)d1*32 + 4*i);
    float4 w = *(const float4*)(g_pw + (size_t)(d1+64)*32 + 4*i);
    Pa[4*i] = u.x; Pa[4*i+1] = u.y; Pa[4*i+2] = u.z; Pa[4*i+3] = u.w;
    Pb[4*i] = w.x; Pb[4*i+1] = w.y; Pb[4*i+2] = w.z; Pb[4*i+3] = w.w;
  }
  const float v1 = g_vw[d1], v2 = g_vw[d1 + 64];
  const float vb = g_scal[0];
  gbar(++bn, bb, tid);

  // ================= main loop: 3 barriers/step =================
  for (int t = 0; t <= 500; ++t) {
    const int rp = t & 1, wp = rp ^ 1;

    // ---- P1: att-LSTM(t) [0..127] | dec-LSTM(t-1) [128..255] ----
    if (bb < 128) {
      if (t < 500) {
        const int j = __builtin_amdgcn_readfirstlane(bb*4 + wv);
        float ai = g_ab[j], af = g_ab[512+j], ag = g_ab[1024+j], ao = g_ab[1536+j];
        dot4f(g_pmt, 256, g_awih + (size_t)j*768, g_awih + (size_t)(512+j)*768,
              g_awih + (size_t)(1024+j)*768, g_awih + (size_t)(1536+j)*768, lane, z, ai, af, ag, ao);
        dot4f(g_ctx, 512, g_awih + (size_t)j*768 + 256, g_awih + (size_t)(512+j)*768 + 256,
              g_awih + (size_t)(1024+j)*768 + 256, g_awih + (size_t)(1536+j)*768 + 256, lane, z, ai, af, ag, ao);
        dot4f(g_hatt + rp*(512*64), 512, g_awhh + (size_t)j*512, g_awhh + (size_t)(512+j)*512,
              g_awhh + (size_t)(1024+j)*512, g_awhh + (size_t)(1536+j)*512, lane, z, ai, af, ag, ao);
        float c = g_catt[j*64 + lane];
        float cn = sigf(af)*c + sigf(ai)*tanhf_fast(ag);
        float hn = sigf(ao)*tanhf_fast(cn);
        g_catt[j*64 + lane] = cn;
        g_hatt[wp*(512*64) + j*64 + lane] = hn;
      }
    } else {
      if (t > 0) {
        const int j = __builtin_amdgcn_readfirstlane((bb-128)*4 + wv);
        float ai = g_db[j], af = g_db[512+j], ag = g_db[1024+j], ao = g_db[1536+j];
        dot4f(g_hatt + rp*(512*64), 512, g_dwih + (size_t)j*1024, g_dwih + (size_t)(512+j)*1024,
              g_dwih + (size_t)(1024+j)*1024, g_dwih + (size_t)(1536+j)*1024, lane, z, ai, af, ag, ao);
        dot4f(g_ctx, 512, g_dwih + (size_t)j*1024 + 512, g_dwih + (size_t)(512+j)*1024 + 512,
              g_dwih + (size_t)(1024+j)*1024 + 512, g_dwih + (size_t)(1536+j)*1024 + 512, lane, z, ai, af, ag, ao);
        dot4f(g_hdec + wp*(512*64), 512, g_dwhh + (size_t)j*512, g_dwhh + (size_t)(512+j)*512,
              g_dwhh + (size_t)(1024+j)*512, g_dwhh + (size_t)(1536+j)*512, lane, z, ai, af, ag, ao);
        float c = g_cdec[j*64 + lane];
        float cn = sigf(af)*c + sigf(ai)*tanhf_fast(ag);
        float hn = sigf(ao)*tanhf_fast(cn);
        g_cdec[j*64 + lane] = cn;
        g_hdec[rp*(512*64) + j*64 + lane] = hn;
      }
    }
    gbar(++bn, bb, tid);

    // ---- P3: energies (q inline) | mel/stop(t-1) | pre1(t+1) ----
    if (t < 500) {
      // q slice for (d1, d1+64, b=eb) from qwT (lane-coalesced) x h_att (VMEM broadcast)
      float q1 = g_qpb[d1], q2 = g_qpb[d1 + 64];
      {
        const float* HA = g_hatt + wp*(512*64) + eb + z;
        for (int k = 0; k < 512; k += 2) {
          float h0 = HA[(k+0)*64];
          float h1 = HA[(k+1)*64];
          q1 = fmaf(g_qwt[(size_t)(k+0)*512 + d1],      h0, q1);
          q2 = fmaf(g_qwt[(size_t)(k+0)*512 + d1 + 64], h0, q2);
          q1 = fmaf(g_qwt[(size_t)(k+1)*512 + d1],      h1, q1);
          q2 = fmaf(g_qwt[(size_t)(k+1)*512 + d1 + 64], h1, q2);
        }
      }
      for (int i = tid; i < 75*32; i += 256) {   // conv into sbuf [75 tt][32 c]
        int ttl = i >> 5, c2 = i & 31;
        int tt = tt0 + ttl;
        float s = g_cb[c2];
        for (int k = 0; k < 31; ++k) {
          int src = tt + k - 15;
          if (src >= 0 && src < 300) {
            s = fmaf(g_cw[c2*62 + k],      g_a[eb*300 + src], s);
            s = fmaf(g_cw[c2*62 + 31 + k], g_acum[eb*300 + src], s);
          }
        }
        sbuf[i] = s;
      }
      __syncthreads();
#pragma unroll
      for (int i = 0; i < 75; ++i) {
        float s1 = q1 + us2f((unsigned short)(mpq[i] & 0xffffu));
        float s2 = q2 + us2f((unsigned short)(mpq[i] >> 16));
#pragma unroll
        for (int c = 0; c < 32; ++c) {
          float cv = sbuf[i*32 + c];
          s1 = fmaf(Pa[c], cv, s1);
          s2 = fmaf(Pb[c], cv, s2);
        }
        float p = v1*tanhf_fast(s1) + v2*tanhf_fast(s2);
#pragma unroll
        for (int m = 32; m >= 1; m >>= 1) p += __shfl_xor(p, m, 64);
        if (lane == 0) part[wv][i] = p;
      }
      __syncthreads();
      if (tid < 75)
        g_e[eb*300 + tt0 + tid] =
            part[0][tid] + part[1][tid] + part[2][tid] + part[3][tid] + vb;
    }
    if (t > 0 && bb < 20) {          // mel(t-1)
      int f2 = bb*256 + tid;         // < 5120
      int b_ = f2 & 63; int m = __builtin_amdgcn_readfirstlane(f2 >> 6);
      const float* HD = g_hdec + rp*(512*64);
      float acc = g_melb[m];
      const float* wr = g_melw + (size_t)m*512 + z;
      for (int k = 0; k < 512; k += 4) {
        float4 u = *(const float4*)(wr + k);
        acc = fmaf(u.x, HD[(k+0)*64 + b_], acc);
        acc = fmaf(u.y, HD[(k+1)*64 + b_], acc);
        acc = fmaf(u.z, HD[(k+2)*64 + b_], acc);
        acc = fmaf(u.w, HD[(k+3)*64 + b_], acc);
      }
      size_t oidx = (size_t)(b_*500 + (t-1))*80 + m;
      if (f32io) outf[oidx] = acc; else outh[oidx] = __float2bfloat16(acc);
    } else if (t > 0 && bb == 20 && tid < 64) {   // stop(t-1)
      int b_ = tid;
      const float* HD = g_hdec + rp*(512*64);
      float acc = g_scal[1];
      const float* wr = g_stopw + z;
      for (int k = 0; k < 512; k += 4) {
        float4 u = *(const float4*)(wr + k);
        acc = fmaf(u.x, HD[(k+0)*64 + b_], acc);
        acc = fmaf(u.y, HD[(k+1)*64 + b_], acc);
        acc = fmaf(u.z, HD[(k+2)*64 + b_], acc);
        acc = fmaf(u.w, HD[(k+3)*64 + b_], acc);
      }
      size_t oidx = 2560000 + b_*500 + (t-1);
      if (f32io) outf[oidx] = acc; else outh[oidx] = __float2bfloat16(acc);
    }
    if (t <= 498 && bb >= 192) {     // pre1(t+1)
      int f3 = (bb - 192)*256 + tid;
      int b_ = f3 & 63; int ii = __builtin_amdgcn_readfirstlane(f3 >> 6);
      float acc = g_b1[ii];
      const float* wr = g_w1 + ii*80 + z;
      const float* mi = g_mel + (size_t)(b_*500 + t + 1)*80;
      for (int m = 0; m < 80; ++m) acc = fmaf(wr[m], mi[m], acc);
      g_pm1t[ii*64 + b_] = fmaxf(acc, 0.f);
    }
    gbar(++bn, bb, tid);

    // ---- P4: softmax + a/a_cum + ctx(t) [0..63] | pre2(t+1) [64..127] ----
    if (t < 500) {
      if (bb < 64) {
        float* pl = sbuf; float* red = sbuf + 304;
        const int b_ = bb;
        const float* Ep = g_e + b_*300;
        float e1 = Ep[tid];
        float e2 = (tid + 256 < 300) ? Ep[tid + 256] : -3e38f;
        red[tid] = fmaxf(e1, e2); __syncthreads();
        for (int s = 128; s > 0; s >>= 1) { if (tid < s) red[tid] = fmaxf(red[tid], red[tid+s]); __syncthreads(); }
        float mx = red[0]; __syncthreads();
        float p1 = __expf(e1 - mx);
        float p2 = (tid + 256 < 300) ? __expf(e2 - mx) : 0.f;
        pl[tid] = p1;
        if (tid + 256 < 300) pl[tid + 256] = p2;
        red[tid] = p1 + p2; __syncthreads();
        for (int s = 128; s > 0; s >>= 1) { if (tid < s) red[tid] += red[tid+s]; __syncthreads(); }
        const float inv = 1.f / red[0];
        float av = pl[tid]*inv;
        g_a[b_*300 + tid] = av; g_acum[b_*300 + tid] += av;
        if (tid + 256 < 300) {
          float av2 = pl[tid+256]*inv;
          g_a[b_*300 + tid+256] = av2; g_acum[b_*300 + tid+256] += av2;
        }
        __syncthreads();
        const float* ep = g_enc + (size_t)(b_*300)*512;
#pragma unroll
        for (int h = 0; h < 2; ++h) {
          int dd = tid + h*256;
          float acc = 0.f;
          for (int tt = 0; tt < 300; ++tt) acc = fmaf(pl[tt], ep[(size_t)tt*512 + dd], acc);
          g_ctx[dd*64 + b_] = acc * inv;
        }
      } else if (bb < 128) {
        if (t <= 498) {   // pre2(t+1)
          int f4 = (bb - 64)*256 + tid;
          int b_ = f4 & 63; int i2 = __builtin_amdgcn_readfirstlane(f4 >> 6);
          float acc = g_b2[i2];
          const float* wr = g_w2 + i2*256 + z;
          for (int k = 0; k < 256; k += 4) {
            float4 u = *(const float4*)(wr + k);
            acc = fmaf(u.x, g_pm1t[(k+0)*64 + b_], acc);
            acc = fmaf(u.y, g_pm1t[(k+1)*64 + b_], acc);
            acc = fmaf(u.z, g_pm1t[(k+2)*64 + b_], acc);
            acc = fmaf(u.w, g_pm1t[(k+3)*64 + b_], acc);
          }
          g_pmt[i2*64 + b_] = fmaxf(acc, 0.f);
        }
      }
    }
    gbar(++bn, bb, tid);
  }
}

// ---------------- host ----------------
extern "C" void kernel_launch(void* const* d_in, const int* in_sizes, int n_in,
                              void* d_out, int out_size, void* d_ws, size_t ws_size,
                              hipStream_t stream) {
  (void)d_ws; (void)ws_size;
  InPtrs P;
  for (int i = 0; i < 28 && i < n_in; ++i) P.p[i] = d_in[i];
  k_convert<<<dim3(2048), dim3(256), 0, stream>>>(P);
  k_dec<<<dim3(NB), dim3(256), 0, stream>>>(d_out);
}